// Round 6
// baseline (21296.439 us; speedup 1.0000x reference)
//
#include <hip/hip_runtime.h>
#include <math.h>

#define B_   16
#define S_   64
#define V_   32000
#define D_   1024
#define W_   4
#define BW   64          // B*W rows
#define L_   75          // min(int(1.1*64+5), 512)
#define EOS_ 2
#define NEGF (-1e9f)

// ---------- top-4 helpers (jax.lax.top_k semantics: desc value, asc index on ties) ----------
__device__ __forceinline__ bool better(float v1, int i1, float v2, int i2) {
    return (v1 > v2) || (v1 == v2 && i1 < i2);
}
__device__ __forceinline__ void ins4(float v, int ix, float tv[4], int ti[4]) {
    if (!better(v, ix, tv[3], ti[3])) return;
    tv[3] = v; ti[3] = ix;
    #pragma unroll
    for (int j = 3; j > 0; --j) {
        if (better(tv[j], ti[j], tv[j-1], ti[j-1])) {
            float fv = tv[j]; tv[j] = tv[j-1]; tv[j-1] = fv;
            int   iv = ti[j]; ti[j] = ti[j-1]; ti[j-1] = iv;
        }
    }
}
// butterfly merge of (running max, running sumexp, top-4) across WIDTH lanes
template<int WIDTH>
__device__ __forceinline__ void bfly(float& m, float& s, float tv[4], int ti[4]) {
    #pragma unroll
    for (int off = 1; off < WIDTH; off <<= 1) {
        const float om = __shfl_xor(m, off), os = __shfl_xor(s, off);
        float ov[4]; int oi[4];
        #pragma unroll
        for (int j = 0; j < 4; ++j) { ov[j] = __shfl_xor(tv[j], off); oi[j] = __shfl_xor(ti[j], off); }
        const float nm = fmaxf(m, om);
        s = s * expf(m - nm) + os * expf(om - nm);
        m = nm;
        #pragma unroll
        for (int j = 0; j < 4; ++j) ins4(ov[j], oi[j], tv, ti);
    }
}

// ---------- encoder context: masked mean of (emb[token] + lang_emb[src_lang]) ----------
__global__ void k_ctx(const int* __restrict__ src, const int* __restrict__ sizes,
                      const int* __restrict__ slang, const float* __restrict__ emb,
                      const float* __restrict__ lemb, float* __restrict__ ctx) {
    const int b = blockIdx.x >> 2;
    const int d = ((blockIdx.x & 3) << 8) + threadIdx.x;
    const int n = sizes[b];
    const float lv = lemb[slang[b]*D_ + d];
    const int* sp = src + b*S_;
    float acc = 0.f;
    for (int s = 0; s < S_; ++s) {
        if (s < n) acc += emb[sp[s]*D_ + d] + lv;   // ref order: (emb + lang) summed over s
    }
    ctx[b*D_ + d] = acc / (float)n;
}

// ---------- state init ----------
__global__ void k_init(const int* __restrict__ sizes, const int* __restrict__ ft,
                       float* __restrict__ scores, int* __restrict__ last, int* __restrict__ fe,
                       int* __restrict__ mlens, int* __restrict__ done, int* __restrict__ T0) {
    const int t = threadIdx.x;
    if (t < BW) {
        scores[t] = ((t & 3) == 0) ? 0.f : NEGF;   // step-1 trick: only beam 0 alive
        last[t]   = ft[t >> 2];
        fe[t]     = -1;                             // first-eos position, -1 = none
    }
    if (t < B_) mlens[t] = min((int)(1.1f * (float)sizes[t] + 5.0f), 512);
    if (t == 0) *done = 0;
    for (int e = t; e < BW * L_; e += 256) {
        int r = e / L_, c = e - r * L_;
        T0[e] = (c == 0) ? ft[r >> 2] : 0;
    }
}

// ---------- initial h (step 1): hT[d*64+r] = tanh((emb[last]+ctx)+lang) ----------
__global__ void k_h0(const int* __restrict__ last, const float* __restrict__ emb,
                     const float* __restrict__ ctx, const float* __restrict__ lemb,
                     const int* __restrict__ tlang, float* __restrict__ hT) {
    for (int j = 0; j < 4; ++j) {
        int e = j * 16384 + blockIdx.x * 256 + threadIdx.x;   // e = d*64 + r
        int r = e & 63, d = e >> 6, b = r >> 2;
        hT[e] = tanhf((emb[last[r]*D_ + d] + ctx[b*D_ + d]) + lemb[tlang[b]*D_ + d]);
    }
}

// ================= GEMM variant 1: BN=64, grid 500, 1 col/lane, 8 waves/SIMD =================
// block 1024 = 16 waves; wave wv owns rows 4wv..4wv+3; lane owns 1 column.
// W register-pipelined 8 deep; h read via wave-uniform pointer -> scalar loads.
__global__ __launch_bounds__(1024, 8) void k_gemm1(const float* __restrict__ hT, const float* __restrict__ w,
        float* __restrict__ pmax, float* __restrict__ psum,
        float* __restrict__ pval, int* __restrict__ pidx, const int* __restrict__ done) {
    if (*done) return;
    const int wv   = __builtin_amdgcn_readfirstlane(threadIdx.x >> 6);
    const int lane = threadIdx.x & 63;
    const int c    = blockIdx.x * 64 + lane;
    const float4* hp4 = (const float4*)hT + wv;
    const float*  wb  = w + c;

    float wbuf[8];
    #pragma unroll
    for (int j = 0; j < 8; ++j) wbuf[j] = wb[(size_t)j * V_];
    float a0 = 0.f, a1 = 0.f, a2 = 0.f, a3 = 0.f;

    for (int k = 0; k < D_ - 8; k += 8) {
        #pragma unroll
        for (int j = 0; j < 8; ++j) {
            const float4 hv = hp4[(k + j) * 16];
            const float  ww = wbuf[j];
            a0 = fmaf(hv.x, ww, a0);
            a1 = fmaf(hv.y, ww, a1);
            a2 = fmaf(hv.z, ww, a2);
            a3 = fmaf(hv.w, ww, a3);
            wbuf[j] = wb[(size_t)(k + j + 8) * V_];   // refill 8 ahead
        }
    }
    #pragma unroll
    for (int j = 0; j < 8; ++j) {                      // tail k = 1016..1023
        const float4 hv = hp4[(D_ - 8 + j) * 16];
        const float  ww = wbuf[j];
        a0 = fmaf(hv.x, ww, a0);
        a1 = fmaf(hv.y, ww, a1);
        a2 = fmaf(hv.z, ww, a2);
        a3 = fmaf(hv.w, ww, a3);
    }

    const float accr[4] = {a0, a1, a2, a3};
    #pragma unroll
    for (int rr = 0; rr < 4; ++rr) {
        float m = accr[rr], s = 1.0f;                  // expf(v-v)=1
        float tv[4]; int ti[4];
        tv[0] = m; ti[0] = c;
        tv[1] = tv[2] = tv[3] = -3.4e38f;
        ti[1] = ti[2] = ti[3] = 0x7fffffff;
        bfly<64>(m, s, tv, ti);
        if (lane == 0) {
            const int o = blockIdx.x * 64 + (wv << 2) + rr;
            pmax[o] = m; psum[o] = s;
            #pragma unroll
            for (int j = 0; j < 4; ++j) { pval[o*4 + j] = tv[j]; pidx[o*4 + j] = ti[j]; }
        }
    }
}

// ================= GEMM variant 2 (fallback): BN=128, grid 250, 2 cols/lane =================
__global__ __launch_bounds__(1024, 4) void k_gemm2(const float* __restrict__ hT, const float* __restrict__ w,
        float* __restrict__ pmax, float* __restrict__ psum,
        float* __restrict__ pval, int* __restrict__ pidx, const int* __restrict__ done) {
    if (*done) return;
    const int wv   = __builtin_amdgcn_readfirstlane(threadIdx.x >> 6);
    const int lane = threadIdx.x & 63;
    const int c    = blockIdx.x * 128 + lane * 2;
    const float4* hp4 = (const float4*)hT + wv;
    const float2* wb  = (const float2*)w + (c >> 1);

    float2 wbuf[8];
    #pragma unroll
    for (int j = 0; j < 8; ++j) wbuf[j] = wb[(size_t)j * (V_/2)];
    float acc[4][2];
    #pragma unroll
    for (int r = 0; r < 4; ++r) { acc[r][0] = 0.f; acc[r][1] = 0.f; }

    for (int k = 0; k < D_ - 8; k += 8) {
        #pragma unroll
        for (int j = 0; j < 8; ++j) {
            const float4 hv = hp4[(k + j) * 16];
            const float2 w2 = wbuf[j];
            acc[0][0] = fmaf(hv.x, w2.x, acc[0][0]);
            acc[0][1] = fmaf(hv.x, w2.y, acc[0][1]);
            acc[1][0] = fmaf(hv.y, w2.x, acc[1][0]);
            acc[1][1] = fmaf(hv.y, w2.y, acc[1][1]);
            acc[2][0] = fmaf(hv.z, w2.x, acc[2][0]);
            acc[2][1] = fmaf(hv.z, w2.y, acc[2][1]);
            acc[3][0] = fmaf(hv.w, w2.x, acc[3][0]);
            acc[3][1] = fmaf(hv.w, w2.y, acc[3][1]);
            wbuf[j] = wb[(size_t)(k + j + 8) * (V_/2)];
        }
    }
    #pragma unroll
    for (int j = 0; j < 8; ++j) {
        const float4 hv = hp4[(D_ - 8 + j) * 16];
        const float2 w2 = wbuf[j];
        acc[0][0] = fmaf(hv.x, w2.x, acc[0][0]);
        acc[0][1] = fmaf(hv.x, w2.y, acc[0][1]);
        acc[1][0] = fmaf(hv.y, w2.x, acc[1][0]);
        acc[1][1] = fmaf(hv.y, w2.y, acc[1][1]);
        acc[2][0] = fmaf(hv.z, w2.x, acc[2][0]);
        acc[2][1] = fmaf(hv.z, w2.y, acc[2][1]);
        acc[3][0] = fmaf(hv.w, w2.x, acc[3][0]);
        acc[3][1] = fmaf(hv.w, w2.y, acc[3][1]);
    }

    #pragma unroll
    for (int rr = 0; rr < 4; ++rr) {
        const float v0 = acc[rr][0], v1 = acc[rr][1];
        float m = fmaxf(v0, v1);
        float s = expf(v0 - m) + expf(v1 - m);
        float tv[4]; int ti[4];
        const bool f = better(v0, c, v1, c + 1);
        tv[0] = f ? v0 : v1;  ti[0] = f ? c : c + 1;
        tv[1] = f ? v1 : v0;  ti[1] = f ? c + 1 : c;
        tv[2] = tv[3] = -3.4e38f;  ti[2] = ti[3] = 0x7fffffff;
        bfly<64>(m, s, tv, ti);
        if (lane == 0) {
            const int o = blockIdx.x * 64 + (wv << 2) + rr;
            pmax[o] = m; psum[o] = s;
            #pragma unroll
            for (int j = 0; j < 4; ++j) { pval[o*4 + j] = tv[j]; pidx[o*4 + j] = ti[j]; }
        }
    }
}

// ---------- per-step merge + softmax/penalty + batch top-4 + state update (1 block) ----------
template<int NBLK>
__global__ __launch_bounds__(1024) void k_update_t(
        int i,
        const float* __restrict__ pmax, const float* __restrict__ psum,
        const float* __restrict__ pval, const int* __restrict__ pidx,
        float* __restrict__ scores, int* __restrict__ last, int* __restrict__ fe,
        const int* __restrict__ mlens, int* __restrict__ done, int* __restrict__ bw) {
    __shared__ float rv[64][4];
    __shared__ int   ri[64][4];
    __shared__ float rM[64], rL[64];
    __shared__ int   sfe[64];
    __shared__ int   s_alive;
    const int t = threadIdx.x;
    if (t == 0) s_alive = 0;
    __syncthreads();

    // ---- phase A: merge NBLK per-block partials into per-row (max, lse, top-4) ----
    {
        const int r = t >> 4, part = t & 15;
        float m = -3.4e38f, s = 0.f;
        float tv[4]; int ti[4];
        #pragma unroll
        for (int j = 0; j < 4; ++j) { tv[j] = -3.4e38f; ti[j] = 0x7fffffff; }
        for (int blk = part; blk < NBLK; blk += 16) {
            const int o = blk * 64 + r;
            const float pm = pmax[o], ps = psum[o];
            const float nm = fmaxf(m, pm);
            s = s * expf(m - nm) + ps * expf(pm - nm);
            m = nm;
            #pragma unroll
            for (int j = 0; j < 4; ++j) ins4(pval[o*4 + j], pidx[o*4 + j], tv, ti);
        }
        bfly<16>(m, s, tv, ti);
        if (part == 0) {
            rM[r] = m; rL[r] = logf(s);
            #pragma unroll
            for (int j = 0; j < 4; ++j) { rv[r][j] = tv[j]; ri[r][j] = ti[j]; }
        }
    }
    if (t < 64) { const int f = fe[t]; sfe[t] = f; if (f < 0) s_alive = 1; }
    __syncthreads();
    const int all_done = (s_alive == 0);

    // ---- phase B: per-batch top-4 over 4 rows x 4 candidates, then state update ----
    if (t < B_) {
        const int b = t;
        if (all_done) {
            if (b == 0) *done = 1;      // k_shuf_h + k_gemm read this as "frozen"
        } else {
            const bool reached = (mlens[b] <= i);          // max_lens < i+1
            const bool r2 = reached && (i > 1);
            float bv[4]; int bi[4];
            #pragma unroll
            for (int j = 0; j < 4; ++j) { bv[j] = -3.4e38f; bi[j] = 0x7fffffff; }
            #pragma unroll
            for (int w = 0; w < 4; ++w) {
                const int rr = b*4 + w;
                const float sc = scores[rr];
                const int f = sfe[rr];
                const bool eos = (f >= 0);
                const bool zero = eos || r2;
                const float len = eos ? (float)(f + 6) : (float)(i + 5);
                const float pen = powf(len / 6.0f, 0.8f);
                if (zero) {
                    const float v = (sc + 0.0f) / pen;      // logp forced to 0 for whole row
                    #pragma unroll
                    for (int j = 0; j < 4; ++j) ins4(v, w*V_ + j, bv, bi);
                } else {
                    const float M = rM[rr], Lg = rL[rr];
                    #pragma unroll
                    for (int j = 0; j < 4; ++j) {
                        const float sh = rv[rr][j] - M;     // ref op order: (z - max) - log(sum)
                        const float lp = sh - Lg;
                        ins4((sc + lp) / pen, w*V_ + ri[rr][j], bv, bi);
                    }
                }
            }
            #pragma unroll
            for (int k = 0; k < 4; ++k) {
                const int idx = r2 ? 0 : bi[k];             // reached -> pad_idx
                const int bm = idx / V_, wd = idx - bm * V_;
                const int rr = b*4 + k;
                scores[rr] = bv[k];                          // top_scores kept even when reached
                last[rr]   = wd;
                bw[rr]     = (bm << 16) | wd;                // packed for k_shuf_h
                const int of = sfe[b*4 + bm];
                fe[rr] = (of >= 0) ? of : ((wd == EOS_) ? i : -1);
            }
        }
    }
}

// ---------- per-step wide pass: token reshuffle + next-step h (64 blocks) ----------
__global__ void k_shuf_h(int i, const int* __restrict__ srcT, int* __restrict__ dstT,
                         const int* __restrict__ bw, const int* __restrict__ done,
                         const int* __restrict__ last,
                         const float* __restrict__ emb, const float* __restrict__ ctx,
                         const float* __restrict__ lemb, const int* __restrict__ tlang,
                         float* __restrict__ hT) {
    const int ad = *done;                      // == this step's all_done (monotone)
    const int t = blockIdx.x * 256 + threadIdx.x;
    if (t < BW * L_) {
        const int rr = t / L_, c = t - rr * L_;
        const int pk = ad ? 0 : bw[rr];
        const int sr = ad ? rr : ((rr & ~3) | (pk >> 16));
        int v = srcT[sr * L_ + c];
        if (!ad && c == i) v = pk & 0xffff;
        dstT[t] = v;
    }
    if (ad) return;                            // frozen: h no longer consumed
    for (int j = 0; j < 4; ++j) {
        const int e = j * 16384 + t;           // e = d*64 + r
        const int r = e & 63, d = e >> 6, b = r >> 2;
        hT[e] = tanhf((emb[last[r]*D_ + d] + ctx[b*D_ + d]) + lemb[tlang[b]*D_ + d]);
    }
}

// ---------- output: tokens[:,0,:] as float, then scores ----------
__global__ void k_out(const int* __restrict__ T, const float* __restrict__ scores,
                      float* __restrict__ out) {
    const int t = blockIdx.x * 256 + threadIdx.x;
    if (t < B_ * L_) {
        const int b = t / L_, p = t - b * L_;
        out[t] = (float)T[(b * 4) * L_ + p];
    } else if (t < B_ * L_ + BW) {
        out[t] = scores[t - B_ * L_];
    }
}

extern "C" void kernel_launch(void* const* d_in, const int* in_sizes, int n_in,
                              void* d_out, int out_size, void* d_ws, size_t ws_size,
                              hipStream_t stream) {
    const int*   src   = (const int*)d_in[0];
    const int*   sizes = (const int*)d_in[1];
    const int*   ft    = (const int*)d_in[2];
    // d_in[3] = src_mask: redundant with src_sizes, unused
    const int*   slang = (const int*)d_in[4];
    const int*   tlang = (const int*)d_in[5];
    // d_in[6] = pad_idx (always 0)
    const float* emb   = (const float*)d_in[7];
    const float* lemb  = (const float*)d_in[8];
    const float* w     = (const float*)d_in[9];

    // ws layout (256B-aligned slots); choose grid-500 partials if ws_size allows,
    // else the proven grid-250 layout. ws_size is call-invariant -> graph-safe.
    char* p = (char*)d_ws;
    auto alloc = [&](size_t bytes) { char* r = p; p += (bytes + 255) & ~255ull; return r; };
    float* ctx    = (float*)alloc(B_ * D_ * 4);        // 65536
    float* hT     = (float*)alloc(BW * D_ * 4);        // 262144
    int*   T0     = (int*)  alloc(BW * L_ * 4);        // 19200
    int*   T1     = (int*)  alloc(BW * L_ * 4);
    float* scores = (float*)alloc(BW * 4);
    int*   last   = (int*)  alloc(BW * 4);
    int*   fe     = (int*)  alloc(BW * 4);
    int*   mlens  = (int*)  alloc(B_ * 4);
    int*   done   = (int*)  alloc(4);
    int*   bwv    = (int*)  alloc(BW * 4);
    const size_t fixed = (size_t)(p - (char*)d_ws);
    const int nblk = (fixed + 500 * 64ull * 40ull + 4096 <= ws_size) ? 500 : 250;
    float* pmax = (float*)alloc((size_t)nblk * 64 * 4);
    float* psum = (float*)alloc((size_t)nblk * 64 * 4);
    float* pval = (float*)alloc((size_t)nblk * 64 * 16);
    int*   pidx = (int*)  alloc((size_t)nblk * 64 * 16);

    k_ctx <<<64, 256, 0, stream>>>(src, sizes, slang, emb, lemb, ctx);
    k_init<<<1, 256, 0, stream>>>(sizes, ft, scores, last, fe, mlens, done, T0);
    k_h0  <<<64, 256, 0, stream>>>(last, emb, ctx, lemb, tlang, hT);

    for (int i = 1; i < L_; ++i) {
        if (nblk == 500)
            k_gemm1<<<500, 1024, 0, stream>>>(hT, w, pmax, psum, pval, pidx, done);
        else
            k_gemm2<<<250, 1024, 0, stream>>>(hT, w, pmax, psum, pval, pidx, done);
        const int* sT = (i & 1) ? T0 : T1;
        int*       dT = (i & 1) ? T1 : T0;
        if (nblk == 500)
            k_update_t<500><<<1, 1024, 0, stream>>>(i, pmax, psum, pval, pidx,
                                                    scores, last, fe, mlens, done, bwv);
        else
            k_update_t<250><<<1, 1024, 0, stream>>>(i, pmax, psum, pval, pidx,
                                                    scores, last, fe, mlens, done, bwv);
        k_shuf_h<<<64, 256, 0, stream>>>(i, sT, dT, bwv, done, last,
                                         emb, ctx, lemb, tlang, hT);
    }
    // 74 steps (even count) -> final tokens land back in T0
    k_out<<<5, 256, 0, stream>>>(T0, scores, (float*)d_out);
}

// Round 7
// 20182.605 us; speedup vs baseline: 1.0552x; 1.0552x over previous
//
#include <hip/hip_runtime.h>
#include <math.h>

#define B_   16
#define S_   64
#define V_   32000
#define D_   1024
#define W_   4
#define BW   64          // B*W rows
#define L_   75          // min(int(1.1*64+5), 512)
#define EOS_ 2
#define NEGF (-1e9f)
#define NB   500         // column-tile blocks (64 cols each)

// ---------- top-4 helpers (jax.lax.top_k semantics: desc value, asc index on ties) ----------
__device__ __forceinline__ bool better(float v1, int i1, float v2, int i2) {
    return (v1 > v2) || (v1 == v2 && i1 < i2);
}
__device__ __forceinline__ void ins4(float v, int ix, float tv[4], int ti[4]) {
    if (!better(v, ix, tv[3], ti[3])) return;
    tv[3] = v; ti[3] = ix;
    #pragma unroll
    for (int j = 3; j > 0; --j) {
        if (better(tv[j], ti[j], tv[j-1], ti[j-1])) {
            float fv = tv[j]; tv[j] = tv[j-1]; tv[j-1] = fv;
            int   iv = ti[j]; ti[j] = ti[j-1]; ti[j-1] = iv;
        }
    }
}
// butterfly merge of (running max, running sumexp, top-4) across WIDTH lanes
template<int WIDTH>
__device__ __forceinline__ void bfly(float& m, float& s, float tv[4], int ti[4]) {
    #pragma unroll
    for (int off = 1; off < WIDTH; off <<= 1) {
        const float om = __shfl_xor(m, off), os = __shfl_xor(s, off);
        float ov[4]; int oi[4];
        #pragma unroll
        for (int j = 0; j < 4; ++j) { ov[j] = __shfl_xor(tv[j], off); oi[j] = __shfl_xor(ti[j], off); }
        const float nm = fmaxf(m, om);
        s = s * expf(m - nm) + os * expf(om - nm);
        m = nm;
        #pragma unroll
        for (int j = 0; j < 4; ++j) ins4(ov[j], oi[j], tv, ti);
    }
}

// ---------- encoder context: masked mean of (emb[token] + lang_emb[src_lang]) ----------
__global__ void k_ctx(const int* __restrict__ src, const int* __restrict__ sizes,
                      const int* __restrict__ slang, const float* __restrict__ emb,
                      const float* __restrict__ lemb, float* __restrict__ ctx) {
    const int b = blockIdx.x >> 2;
    const int d = ((blockIdx.x & 3) << 8) + threadIdx.x;
    const int n = sizes[b];
    const float lv = lemb[slang[b]*D_ + d];
    const int* sp = src + b*S_;
    float acc = 0.f;
    for (int s = 0; s < S_; ++s) {
        if (s < n) acc += emb[sp[s]*D_ + d] + lv;   // ref order: (emb + lang) summed over s
    }
    ctx[b*D_ + d] = acc / (float)n;
}

// ---------- state init ----------
__global__ void k_init(const int* __restrict__ sizes, const int* __restrict__ ft,
                       float* __restrict__ scores, int* __restrict__ last, int* __restrict__ fe,
                       int* __restrict__ mlens, int* __restrict__ done, int* __restrict__ T0) {
    const int t = threadIdx.x;
    if (t < BW) {
        scores[t] = ((t & 3) == 0) ? 0.f : NEGF;   // step-1 trick: only beam 0 alive
        last[t]   = ft[t >> 2];
        fe[t]     = -1;                             // first-eos position, -1 = none
    }
    if (t < B_) mlens[t] = min((int)(1.1f * (float)sizes[t] + 5.0f), 512);
    if (t == 0) *done = 0;
    for (int e = t; e < BW * L_; e += 256) {
        int r = e / L_, c = e - r * L_;
        T0[e] = (c == 0) ? ft[r >> 2] : 0;
    }
}

// ---------- initial h (step 1): hT[d*64+r] = tanh((emb[last]+ctx)+lang) ----------
__global__ void k_h0(const int* __restrict__ last, const float* __restrict__ emb,
                     const float* __restrict__ ctx, const float* __restrict__ lemb,
                     const int* __restrict__ tlang, float* __restrict__ hT) {
    for (int j = 0; j < 4; ++j) {
        int e = j * 16384 + blockIdx.x * 256 + threadIdx.x;   // e = d*64 + r
        int r = e & 63, d = e >> 6, b = r >> 2;
        hT[e] = tanhf((emb[last[r]*D_ + d] + ctx[b*D_ + d]) + lemb[tlang[b]*D_ + d]);
    }
}

// ================= GEMM: LDS-staged W, grid 500, block 512 (8 waves) =================
// Wave wv owns rows 8wv..8wv+7; lane owns 1 column (64 cols/block).
// W tile double-buffered in LDS (BK=64 chunks, reg-staged): block's waves SHARE the
// W load (round-6 kernel loaded W 16x redundantly -> 75% of VALU issue was overhead).
// Per k-step: 8 FMA + 1 ds_read_b32 (2-way bank = free) + h via wave-uniform s_load.
__global__ __launch_bounds__(512, 4) void k_gemm(const float* __restrict__ hT, const float* __restrict__ w,
        float* __restrict__ pmax, float* __restrict__ psum,
        float* __restrict__ pval, int* __restrict__ pidx, const int* __restrict__ done) {
    if (*done) return;
    __shared__ float sw[2][64 * 64];                 // [buf][k(64) x col(64)]
    const int t    = threadIdx.x;
    const int wv   = __builtin_amdgcn_readfirstlane(t >> 6);
    const int lane = t & 63;
    const int c0   = blockIdx.x << 6;
    const int c    = c0 + lane;
    const float4* hp = (const float4*)hT + (wv << 1); // rows 8wv..: 2 float4 per k

    // stage mapping: thread t fills float4 slots s=t and s=t+512 of the 1024-slot chunk
    // slot s -> (k_sub = s>>4, colgrp = s&15); chunk ch covers k = ch*64 + k_sub
    const float* gsrc = w + (size_t)(t >> 4) * V_ + (c0 + ((t & 15) << 2));
    float4* ldst = (float4*)sw;                      // slot write: [buf*1024 + s]

    // prologue: chunk 0
    float4 st0 = *(const float4*)gsrc;
    float4 st1 = *(const float4*)(gsrc + (size_t)32 * V_);
    ldst[t]       = st0;
    ldst[t + 512] = st1;
    __syncthreads();

    float a[8];
    #pragma unroll
    for (int r = 0; r < 8; ++r) a[r] = 0.f;

    int cur = 0;
    for (int ch = 0; ch < 16; ++ch) {
        if (ch < 15) {                               // issue next chunk's global loads
            const float* g2 = gsrc + (size_t)(ch + 1) * 64 * V_;
            st0 = *(const float4*)g2;
            st1 = *(const float4*)(g2 + (size_t)32 * V_);
        }
        const float* bufc = &sw[cur][0];
        const int k0 = ch << 6;
        #pragma unroll 8
        for (int k = 0; k < 64; ++k) {
            const float  ww = bufc[(k << 6) + lane];
            const float4 ha = hp[(size_t)(k0 + k) << 4];
            const float4 hb = hp[(((size_t)(k0 + k)) << 4) + 1];
            a[0] = fmaf(ha.x, ww, a[0]);
            a[1] = fmaf(ha.y, ww, a[1]);
            a[2] = fmaf(ha.z, ww, a[2]);
            a[3] = fmaf(ha.w, ww, a[3]);
            a[4] = fmaf(hb.x, ww, a[4]);
            a[5] = fmaf(hb.y, ww, a[5]);
            a[6] = fmaf(hb.z, ww, a[6]);
            a[7] = fmaf(hb.w, ww, a[7]);
        }
        if (ch < 15) {                               // write next chunk, flip, sync
            float4* l2 = ldst + ((cur ^ 1) << 10);
            l2[t]       = st0;                        // waits vmcnt on st0/st1 here --
            l2[t + 512] = st1;                        // latency hidden under 64-k compute
            cur ^= 1;
            __syncthreads();
        }
    }

    // per-row wave reduction across 64 lanes (=64 cols): (max, sumexp) + top-4
    #pragma unroll
    for (int rr = 0; rr < 8; ++rr) {
        float m = a[rr], s = 1.0f;                   // expf(v-v)=1
        float tv[4]; int ti[4];
        tv[0] = m; ti[0] = c;
        tv[1] = tv[2] = tv[3] = -3.4e38f;
        ti[1] = ti[2] = ti[3] = 0x7fffffff;
        bfly<64>(m, s, tv, ti);
        if (lane == 0) {
            const int o = blockIdx.x * 64 + (wv << 3) + rr;
            pmax[o] = m; psum[o] = s;
            #pragma unroll
            for (int j = 0; j < 4; ++j) { pval[o*4 + j] = tv[j]; pidx[o*4 + j] = ti[j]; }
        }
    }
}

// ---------- per-step merge + softmax/penalty + batch top-4 + state update (1 block) ----------
template<int NBLK>
__global__ __launch_bounds__(1024) void k_update_t(
        int i,
        const float* __restrict__ pmax, const float* __restrict__ psum,
        const float* __restrict__ pval, const int* __restrict__ pidx,
        float* __restrict__ scores, int* __restrict__ last, int* __restrict__ fe,
        const int* __restrict__ mlens, int* __restrict__ done, int* __restrict__ bw) {
    __shared__ float rv[64][4];
    __shared__ int   ri[64][4];
    __shared__ float rM[64], rL[64];
    __shared__ int   sfe[64];
    __shared__ int   s_alive;
    const int t = threadIdx.x;
    if (t == 0) s_alive = 0;
    __syncthreads();

    // ---- phase A: merge NBLK per-block partials into per-row (max, lse, top-4) ----
    {
        const int r = t >> 4, part = t & 15;
        float m = -3.4e38f, s = 0.f;
        float tv[4]; int ti[4];
        #pragma unroll
        for (int j = 0; j < 4; ++j) { tv[j] = -3.4e38f; ti[j] = 0x7fffffff; }
        for (int blk = part; blk < NBLK; blk += 16) {
            const int o = blk * 64 + r;
            const float pm = pmax[o], ps = psum[o];
            const float nm = fmaxf(m, pm);
            s = s * expf(m - nm) + ps * expf(pm - nm);
            m = nm;
            #pragma unroll
            for (int j = 0; j < 4; ++j) ins4(pval[o*4 + j], pidx[o*4 + j], tv, ti);
        }
        bfly<16>(m, s, tv, ti);
        if (part == 0) {
            rM[r] = m; rL[r] = logf(s);
            #pragma unroll
            for (int j = 0; j < 4; ++j) { rv[r][j] = tv[j]; ri[r][j] = ti[j]; }
        }
    }
    if (t < 64) { const int f = fe[t]; sfe[t] = f; if (f < 0) s_alive = 1; }
    __syncthreads();
    const int all_done = (s_alive == 0);

    // ---- phase B: per-batch top-4 over 4 rows x 4 candidates, then state update ----
    if (t < B_) {
        const int b = t;
        if (all_done) {
            if (b == 0) *done = 1;      // k_shuf_h + k_gemm read this as "frozen"
        } else {
            const bool reached = (mlens[b] <= i);          // max_lens < i+1
            const bool r2 = reached && (i > 1);
            float bv[4]; int bi[4];
            #pragma unroll
            for (int j = 0; j < 4; ++j) { bv[j] = -3.4e38f; bi[j] = 0x7fffffff; }
            #pragma unroll
            for (int w = 0; w < 4; ++w) {
                const int rr = b*4 + w;
                const float sc = scores[rr];
                const int f = sfe[rr];
                const bool eos = (f >= 0);
                const bool zero = eos || r2;
                const float len = eos ? (float)(f + 6) : (float)(i + 5);
                const float pen = powf(len / 6.0f, 0.8f);
                if (zero) {
                    const float v = (sc + 0.0f) / pen;      // logp forced to 0 for whole row
                    #pragma unroll
                    for (int j = 0; j < 4; ++j) ins4(v, w*V_ + j, bv, bi);
                } else {
                    const float M = rM[rr], Lg = rL[rr];
                    #pragma unroll
                    for (int j = 0; j < 4; ++j) {
                        const float sh = rv[rr][j] - M;     // ref op order: (z - max) - log(sum)
                        const float lp = sh - Lg;
                        ins4((sc + lp) / pen, w*V_ + ri[rr][j], bv, bi);
                    }
                }
            }
            #pragma unroll
            for (int k = 0; k < 4; ++k) {
                const int idx = r2 ? 0 : bi[k];             // reached -> pad_idx
                const int bm = idx / V_, wd = idx - bm * V_;
                const int rr = b*4 + k;
                scores[rr] = bv[k];                          // top_scores kept even when reached
                last[rr]   = wd;
                bw[rr]     = (bm << 16) | wd;                // packed for k_shuf_h
                const int of = sfe[b*4 + bm];
                fe[rr] = (of >= 0) ? of : ((wd == EOS_) ? i : -1);
            }
        }
    }
}

// ---------- per-step wide pass: token reshuffle + next-step h (64 blocks) ----------
__global__ void k_shuf_h(int i, const int* __restrict__ srcT, int* __restrict__ dstT,
                         const int* __restrict__ bw, const int* __restrict__ done,
                         const int* __restrict__ last,
                         const float* __restrict__ emb, const float* __restrict__ ctx,
                         const float* __restrict__ lemb, const int* __restrict__ tlang,
                         float* __restrict__ hT) {
    const int ad = *done;                      // == this step's all_done (monotone)
    const int t = blockIdx.x * 256 + threadIdx.x;
    if (t < BW * L_) {
        const int rr = t / L_, c = t - rr * L_;
        const int pk = ad ? 0 : bw[rr];
        const int sr = ad ? rr : ((rr & ~3) | (pk >> 16));
        int v = srcT[sr * L_ + c];
        if (!ad && c == i) v = pk & 0xffff;
        dstT[t] = v;
    }
    if (ad) return;                            // frozen: h no longer consumed
    for (int j = 0; j < 4; ++j) {
        const int e = j * 16384 + t;           // e = d*64 + r
        const int r = e & 63, d = e >> 6, b = r >> 2;
        hT[e] = tanhf((emb[last[r]*D_ + d] + ctx[b*D_ + d]) + lemb[tlang[b]*D_ + d]);
    }
}

// ---------- output: tokens[:,0,:] as float, then scores ----------
__global__ void k_out(const int* __restrict__ T, const float* __restrict__ scores,
                      float* __restrict__ out) {
    const int t = blockIdx.x * 256 + threadIdx.x;
    if (t < B_ * L_) {
        const int b = t / L_, p = t - b * L_;
        out[t] = (float)T[(b * 4) * L_ + p];
    } else if (t < B_ * L_ + BW) {
        out[t] = scores[t - B_ * L_];
    }
}

extern "C" void kernel_launch(void* const* d_in, const int* in_sizes, int n_in,
                              void* d_out, int out_size, void* d_ws, size_t ws_size,
                              hipStream_t stream) {
    const int*   src   = (const int*)d_in[0];
    const int*   sizes = (const int*)d_in[1];
    const int*   ft    = (const int*)d_in[2];
    // d_in[3] = src_mask: redundant with src_sizes, unused
    const int*   slang = (const int*)d_in[4];
    const int*   tlang = (const int*)d_in[5];
    // d_in[6] = pad_idx (always 0)
    const float* emb   = (const float*)d_in[7];
    const float* lemb  = (const float*)d_in[8];
    const float* w     = (const float*)d_in[9];

    // ws layout (256B-aligned slots) — same as the round-6 run that passed (1.65 MB).
    char* p = (char*)d_ws;
    auto alloc = [&](size_t bytes) { char* r = p; p += (bytes + 255) & ~255ull; return r; };
    float* ctx    = (float*)alloc(B_ * D_ * 4);
    float* hT     = (float*)alloc(BW * D_ * 4);
    int*   T0     = (int*)  alloc(BW * L_ * 4);
    int*   T1     = (int*)  alloc(BW * L_ * 4);
    float* scores = (float*)alloc(BW * 4);
    int*   last   = (int*)  alloc(BW * 4);
    int*   fe     = (int*)  alloc(BW * 4);
    int*   mlens  = (int*)  alloc(B_ * 4);
    int*   done   = (int*)  alloc(4);
    int*   bwv    = (int*)  alloc(BW * 4);
    float* pmax   = (float*)alloc((size_t)NB * 64 * 4);
    float* psum   = (float*)alloc((size_t)NB * 64 * 4);
    float* pval   = (float*)alloc((size_t)NB * 64 * 16);
    int*   pidx   = (int*)  alloc((size_t)NB * 64 * 16);

    k_ctx <<<64, 256, 0, stream>>>(src, sizes, slang, emb, lemb, ctx);
    k_init<<<1, 256, 0, stream>>>(sizes, ft, scores, last, fe, mlens, done, T0);
    k_h0  <<<64, 256, 0, stream>>>(last, emb, ctx, lemb, tlang, hT);

    for (int i = 1; i < L_; ++i) {
        k_gemm<<<NB, 512, 0, stream>>>(hT, w, pmax, psum, pval, pidx, done);
        const int* sT = (i & 1) ? T0 : T1;
        int*       dT = (i & 1) ? T1 : T0;
        k_update_t<NB><<<1, 1024, 0, stream>>>(i, pmax, psum, pval, pidx,
                                               scores, last, fe, mlens, done, bwv);
        k_shuf_h<<<64, 256, 0, stream>>>(i, sT, dT, bwv, done, last,
                                         emb, ctx, lemb, tlang, hT);
    }
    // 74 steps (even count) -> final tokens land back in T0
    k_out<<<5, 256, 0, stream>>>(T0, scores, (float*)d_out);
}

// Round 11
// 10960.544 us; speedup vs baseline: 1.9430x; 1.8414x over previous
//
#include <hip/hip_runtime.h>
#include <math.h>

#define B_   16
#define S_   64
#define V_   32000
#define D_   1024
#define W_   4
#define BW   64          // B*W rows
#define L_   75          // min(int(1.1*64+5), 512)
#define EOS_ 2
#define NEGF (-1e9f)
#define NB   500         // column-tile blocks (64 cols each)

// ---------- top-4 helpers (jax.lax.top_k semantics: desc value, asc index on ties) ----------
__device__ __forceinline__ bool better(float v1, int i1, float v2, int i2) {
    return (v1 > v2) || (v1 == v2 && i1 < i2);
}
__device__ __forceinline__ void ins4(float v, int ix, float tv[4], int ti[4]) {
    if (!better(v, ix, tv[3], ti[3])) return;
    tv[3] = v; ti[3] = ix;
    #pragma unroll
    for (int j = 3; j > 0; --j) {
        if (better(tv[j], ti[j], tv[j-1], ti[j-1])) {
            float fv = tv[j]; tv[j] = tv[j-1]; tv[j-1] = fv;
            int   iv = ti[j]; ti[j] = ti[j-1]; ti[j-1] = iv;
        }
    }
}
// butterfly merge of (running max, running sumexp, top-4) across WIDTH lanes
template<int WIDTH>
__device__ __forceinline__ void bfly(float& m, float& s, float tv[4], int ti[4]) {
    #pragma unroll
    for (int off = 1; off < WIDTH; off <<= 1) {
        const float om = __shfl_xor(m, off), os = __shfl_xor(s, off);
        float ov[4]; int oi[4];
        #pragma unroll
        for (int j = 0; j < 4; ++j) { ov[j] = __shfl_xor(tv[j], off); oi[j] = __shfl_xor(ti[j], off); }
        const float nm = fmaxf(m, om);
        s = s * expf(m - nm) + os * expf(om - nm);
        m = nm;
        #pragma unroll
        for (int j = 0; j < 4; ++j) ins4(ov[j], oi[j], tv, ti);
    }
}

// ---------- encoder context: masked mean of (emb[token] + lang_emb[src_lang]) ----------
__global__ void k_ctx(const int* __restrict__ src, const int* __restrict__ sizes,
                      const int* __restrict__ slang, const float* __restrict__ emb,
                      const float* __restrict__ lemb, float* __restrict__ ctx) {
    const int b = blockIdx.x >> 2;
    const int d = ((blockIdx.x & 3) << 8) + threadIdx.x;
    const int n = sizes[b];
    const float lv = lemb[slang[b]*D_ + d];
    const int* sp = src + b*S_;
    float acc = 0.f;
    for (int s = 0; s < S_; ++s) {
        if (s < n) acc += emb[sp[s]*D_ + d] + lv;   // ref order: (emb + lang) summed over s
    }
    ctx[b*D_ + d] = acc / (float)n;
}

// ---------- state init ----------
__global__ void k_init(const int* __restrict__ sizes, const int* __restrict__ ft,
                       float* __restrict__ scores, int* __restrict__ last, int* __restrict__ fe,
                       int* __restrict__ mlens, int* __restrict__ done, int* __restrict__ T0) {
    const int t = threadIdx.x;
    if (t < BW) {
        scores[t] = ((t & 3) == 0) ? 0.f : NEGF;   // step-1 trick: only beam 0 alive
        last[t]   = ft[t >> 2];
        fe[t]     = -1;                             // first-eos position, -1 = none
    }
    if (t < B_) mlens[t] = min((int)(1.1f * (float)sizes[t] + 5.0f), 512);
    if (t == 0) *done = 0;
    for (int e = t; e < BW * L_; e += 256) {
        int r = e / L_, c = e - r * L_;
        T0[e] = (c == 0) ? ft[r >> 2] : 0;
    }
}

// ---------- initial h (step 1): hT[d*64+r] = tanh((emb[last]+ctx)+lang) ----------
__global__ void k_h0(const int* __restrict__ last, const float* __restrict__ emb,
                     const float* __restrict__ ctx, const float* __restrict__ lemb,
                     const int* __restrict__ tlang, float* __restrict__ hT) {
    for (int j = 0; j < 4; ++j) {
        int e = j * 16384 + blockIdx.x * 256 + threadIdx.x;   // e = d*64 + r
        int r = e & 63, d = e >> 6, b = r >> 2;
        hT[e] = tanhf((emb[last[r]*D_ + d] + ctx[b*D_ + d]) + lemb[tlang[b]*D_ + d]);
    }
}

// ================= GEMM: LDS-staged W, grid 500, block 512 (8 waves) =================
// Wave wv owns rows 8wv..8wv+7; lane owns 1 column (64 cols/block).
// Partials written TRANSPOSED (o = row*NB + blk) so k_merge reads coalesce.
__global__ __launch_bounds__(512, 4) void k_gemm(const float* __restrict__ hT, const float* __restrict__ w,
        float* __restrict__ pmax, float* __restrict__ psum,
        float* __restrict__ pval, int* __restrict__ pidx, const int* __restrict__ done) {
    if (*done) return;
    __shared__ float sw[2][64 * 64];                 // [buf][k(64) x col(64)]
    const int t    = threadIdx.x;
    const int wv   = __builtin_amdgcn_readfirstlane(t >> 6);
    const int lane = t & 63;
    const int c0   = blockIdx.x << 6;
    const int c    = c0 + lane;
    const float4* hp = (const float4*)hT + (wv << 1); // rows 8wv..: 2 float4 per k

    // stage mapping: thread t fills float4 slots s=t and s=t+512 of the 1024-slot chunk
    const float* gsrc = w + (size_t)(t >> 4) * V_ + (c0 + ((t & 15) << 2));
    float4* ldst = (float4*)sw;                      // slot write: [buf*1024 + s]

    // prologue: chunk 0
    float4 st0 = *(const float4*)gsrc;
    float4 st1 = *(const float4*)(gsrc + (size_t)32 * V_);
    ldst[t]       = st0;
    ldst[t + 512] = st1;
    __syncthreads();

    float a[8];
    #pragma unroll
    for (int r = 0; r < 8; ++r) a[r] = 0.f;

    int cur = 0;
    for (int ch = 0; ch < 16; ++ch) {
        if (ch < 15) {                               // issue next chunk's global loads
            const float* g2 = gsrc + (size_t)(ch + 1) * 64 * V_;
            st0 = *(const float4*)g2;
            st1 = *(const float4*)(g2 + (size_t)32 * V_);
        }
        const float* bufc = &sw[cur][0];
        const int k0 = ch << 6;
        #pragma unroll 8
        for (int k = 0; k < 64; ++k) {
            const float  ww = bufc[(k << 6) + lane];
            const float4 ha = hp[(size_t)(k0 + k) << 4];
            const float4 hb = hp[(((size_t)(k0 + k)) << 4) + 1];
            a[0] = fmaf(ha.x, ww, a[0]);
            a[1] = fmaf(ha.y, ww, a[1]);
            a[2] = fmaf(ha.z, ww, a[2]);
            a[3] = fmaf(ha.w, ww, a[3]);
            a[4] = fmaf(hb.x, ww, a[4]);
            a[5] = fmaf(hb.y, ww, a[5]);
            a[6] = fmaf(hb.z, ww, a[6]);
            a[7] = fmaf(hb.w, ww, a[7]);
        }
        if (ch < 15) {                               // write next chunk, flip, sync
            float4* l2 = ldst + ((cur ^ 1) << 10);
            l2[t]       = st0;
            l2[t + 512] = st1;
            cur ^= 1;
            __syncthreads();
        }
    }

    // per-row wave reduction across 64 lanes (=64 cols): (max, sumexp) + top-4
    #pragma unroll
    for (int rr = 0; rr < 8; ++rr) {
        float m = a[rr], s = 1.0f;                   // expf(v-v)=1
        float tv[4]; int ti[4];
        tv[0] = m; ti[0] = c;
        tv[1] = tv[2] = tv[3] = -3.4e38f;
        ti[1] = ti[2] = ti[3] = 0x7fffffff;
        bfly<64>(m, s, tv, ti);
        if (lane == 0) {
            const int o = ((wv << 3) + rr) * NB + (int)blockIdx.x;   // row-major: coalesced merge reads
            pmax[o] = m; psum[o] = s;
            ((float4*)pval)[o] = make_float4(tv[0], tv[1], tv[2], tv[3]);
            ((int4*)pidx)[o]   = make_int4(ti[0], ti[1], ti[2], ti[3]);
        }
    }
}

// ---------- per-step merge, grid 64 (block = one row): 500 partials -> row result ----------
// Round-7 lesson: the 1-block 31-iteration strided merge was 147.7 us (channel-camping,
// single-CU latency-bound). Now: thread j owns partial j (coalesced float4/int4), wave
// butterfly + 8-wave LDS combine, 64 CUs in parallel.
__global__ __launch_bounds__(512) void k_merge(
        const float* __restrict__ pmax, const float* __restrict__ psum,
        const float* __restrict__ pval, const int* __restrict__ pidx,
        const int* __restrict__ done,
        float* __restrict__ rowm, float* __restrict__ rows,
        float* __restrict__ rowv, int* __restrict__ rowi) {
    if (*done) return;
    const int r = blockIdx.x;
    const int t = threadIdx.x;
    float m = -3.4e38f, s = 0.f;
    float tv[4]; int ti[4];
    tv[0] = tv[1] = tv[2] = tv[3] = -3.4e38f;
    ti[0] = ti[1] = ti[2] = ti[3] = 0x7fffffff;
    if (t < NB) {
        const int o = r * NB + t;
        m = pmax[o];
        s = psum[o];
        const float4 v4 = ((const float4*)pval)[o];
        const int4   i4 = ((const int4*)pidx)[o];
        tv[0] = v4.x; tv[1] = v4.y; tv[2] = v4.z; tv[3] = v4.w;   // already sorted desc
        ti[0] = i4.x; ti[1] = i4.y; ti[2] = i4.z; ti[3] = i4.w;
    }
    bfly<64>(m, s, tv, ti);

    __shared__ float sm[8], ss[8], stv[8][4];
    __shared__ int   sti[8][4];
    const int wv = t >> 6, lane = t & 63;
    if (lane == 0) {
        sm[wv] = m; ss[wv] = s;
        #pragma unroll
        for (int j = 0; j < 4; ++j) { stv[wv][j] = tv[j]; sti[wv][j] = ti[j]; }
    }
    __syncthreads();
    if (t == 0) {
        for (int q = 1; q < 8; ++q) {
            const float om = sm[q], os = ss[q];
            const float nm = fmaxf(m, om);
            s = s * expf(m - nm) + os * expf(om - nm);
            m = nm;
            #pragma unroll
            for (int j = 0; j < 4; ++j) ins4(stv[q][j], sti[q][j], tv, ti);
        }
        rowm[r] = m; rows[r] = s;
        ((float4*)rowv)[r] = make_float4(tv[0], tv[1], tv[2], tv[3]);
        ((int4*)rowi)[r]   = make_int4(ti[0], ti[1], ti[2], ti[3]);
    }
}

// ---------- per-step: softmax/penalty + batch top-4 + state update (1 block, 64 thr) ----------
__global__ __launch_bounds__(64) void k_upd2(
        int i,
        const float* __restrict__ rowm, const float* __restrict__ rows,
        const float* __restrict__ rowv, const int* __restrict__ rowi,
        float* __restrict__ scores, int* __restrict__ last, int* __restrict__ fe,
        const int* __restrict__ mlens, int* __restrict__ done, int* __restrict__ bw) {
    __shared__ float rM[64], rL[64], rv[64][4];
    __shared__ int   ri[64][4], sfe[64];
    __shared__ int   s_alive;
    const int t = threadIdx.x;
    if (t == 0) s_alive = 0;
    __syncthreads();
    {
        rM[t] = rowm[t];
        rL[t] = logf(rows[t]);
        const float4 v4 = ((const float4*)rowv)[t];
        const int4   i4 = ((const int4*)rowi)[t];
        rv[t][0] = v4.x; rv[t][1] = v4.y; rv[t][2] = v4.z; rv[t][3] = v4.w;
        ri[t][0] = i4.x; ri[t][1] = i4.y; ri[t][2] = i4.z; ri[t][3] = i4.w;
        const int f = fe[t]; sfe[t] = f; if (f < 0) s_alive = 1;
    }
    __syncthreads();
    const int all_done = (s_alive == 0);

    if (t < B_) {
        const int b = t;
        if (all_done) {
            if (b == 0) *done = 1;      // k_gemm/k_merge/k_shuf_h read this as "frozen"
        } else {
            const bool reached = (mlens[b] <= i);          // max_lens < i+1
            const bool r2 = reached && (i > 1);
            float bv[4]; int bi[4];
            #pragma unroll
            for (int j = 0; j < 4; ++j) { bv[j] = -3.4e38f; bi[j] = 0x7fffffff; }
            #pragma unroll
            for (int w = 0; w < 4; ++w) {
                const int rr = b*4 + w;
                const float sc = scores[rr];
                const int f = sfe[rr];
                const bool eos = (f >= 0);
                const bool zero = eos || r2;
                const float len = eos ? (float)(f + 6) : (float)(i + 5);
                const float pen = powf(len / 6.0f, 0.8f);
                if (zero) {
                    const float v = (sc + 0.0f) / pen;      // logp forced to 0 for whole row
                    #pragma unroll
                    for (int j = 0; j < 4; ++j) ins4(v, w*V_ + j, bv, bi);
                } else {
                    const float M = rM[rr], Lg = rL[rr];
                    #pragma unroll
                    for (int j = 0; j < 4; ++j) {
                        const float sh = rv[rr][j] - M;     // ref op order: (z - max) - log(sum)
                        const float lp = sh - Lg;
                        ins4((sc + lp) / pen, w*V_ + ri[rr][j], bv, bi);
                    }
                }
            }
            #pragma unroll
            for (int k = 0; k < 4; ++k) {
                const int idx = r2 ? 0 : bi[k];             // reached -> pad_idx
                const int bm = idx / V_, wd = idx - bm * V_;
                const int rr = b*4 + k;
                scores[rr] = bv[k];                          // top_scores kept even when reached
                last[rr]   = wd;
                bw[rr]     = (bm << 16) | wd;                // packed for k_shuf_h
                const int of = sfe[b*4 + bm];
                fe[rr] = (of >= 0) ? of : ((wd == EOS_) ? i : -1);
            }
        }
    }
}

// ---------- per-step wide pass: token reshuffle + next-step h (64 blocks) ----------
__global__ void k_shuf_h(int i, const int* __restrict__ srcT, int* __restrict__ dstT,
                         const int* __restrict__ bw, const int* __restrict__ done,
                         const int* __restrict__ last,
                         const float* __restrict__ emb, const float* __restrict__ ctx,
                         const float* __restrict__ lemb, const int* __restrict__ tlang,
                         float* __restrict__ hT) {
    const int ad = *done;                      // == this step's all_done (monotone)
    const int t = blockIdx.x * 256 + threadIdx.x;
    if (t < BW * L_) {
        const int rr = t / L_, c = t - rr * L_;
        const int pk = ad ? 0 : bw[rr];
        const int sr = ad ? rr : ((rr & ~3) | (pk >> 16));
        int v = srcT[sr * L_ + c];
        if (!ad && c == i) v = pk & 0xffff;
        dstT[t] = v;
    }
    if (ad) return;                            // frozen: h no longer consumed
    for (int j = 0; j < 4; ++j) {
        const int e = j * 16384 + t;           // e = d*64 + r
        const int r = e & 63, d = e >> 6, b = r >> 2;
        hT[e] = tanhf((emb[last[r]*D_ + d] + ctx[b*D_ + d]) + lemb[tlang[b]*D_ + d]);
    }
}

// ---------- output: tokens[:,0,:] as float, then scores ----------
__global__ void k_out(const int* __restrict__ T, const float* __restrict__ scores,
                      float* __restrict__ out) {
    const int t = blockIdx.x * 256 + threadIdx.x;
    if (t < B_ * L_) {
        const int b = t / L_, p = t - b * L_;
        out[t] = (float)T[(b * 4) * L_ + p];
    } else if (t < B_ * L_ + BW) {
        out[t] = scores[t - B_ * L_];
    }
}

extern "C" void kernel_launch(void* const* d_in, const int* in_sizes, int n_in,
                              void* d_out, int out_size, void* d_ws, size_t ws_size,
                              hipStream_t stream) {
    const int*   src   = (const int*)d_in[0];
    const int*   sizes = (const int*)d_in[1];
    const int*   ft    = (const int*)d_in[2];
    // d_in[3] = src_mask: redundant with src_sizes, unused
    const int*   slang = (const int*)d_in[4];
    const int*   tlang = (const int*)d_in[5];
    // d_in[6] = pad_idx (always 0)
    const float* emb   = (const float*)d_in[7];
    const float* lemb  = (const float*)d_in[8];
    const float* w     = (const float*)d_in[9];

    // ws layout (256B-aligned slots) — ~1.65 MB total, proven to fit in rounds 6-7.
    char* p = (char*)d_ws;
    auto alloc = [&](size_t bytes) { char* r = p; p += (bytes + 255) & ~255ull; return r; };
    float* ctx    = (float*)alloc(B_ * D_ * 4);
    float* hT     = (float*)alloc(BW * D_ * 4);
    int*   T0     = (int*)  alloc(BW * L_ * 4);
    int*   T1     = (int*)  alloc(BW * L_ * 4);
    float* scores = (float*)alloc(BW * 4);
    int*   last   = (int*)  alloc(BW * 4);
    int*   fe     = (int*)  alloc(BW * 4);
    int*   mlens  = (int*)  alloc(B_ * 4);
    int*   done   = (int*)  alloc(4);
    int*   bwv    = (int*)  alloc(BW * 4);
    float* pmax   = (float*)alloc((size_t)NB * 64 * 4);
    float* psum   = (float*)alloc((size_t)NB * 64 * 4);
    float* pval   = (float*)alloc((size_t)NB * 64 * 16);
    int*   pidx   = (int*)  alloc((size_t)NB * 64 * 16);
    float* rowm   = (float*)alloc(64 * 4);
    float* rows   = (float*)alloc(64 * 4);
    float* rowv   = (float*)alloc(64 * 16);
    int*   rowi   = (int*)  alloc(64 * 16);

    k_ctx <<<64, 256, 0, stream>>>(src, sizes, slang, emb, lemb, ctx);
    k_init<<<1, 256, 0, stream>>>(sizes, ft, scores, last, fe, mlens, done, T0);
    k_h0  <<<64, 256, 0, stream>>>(last, emb, ctx, lemb, tlang, hT);

    for (int i = 1; i < L_; ++i) {
        k_gemm<<<NB, 512, 0, stream>>>(hT, w, pmax, psum, pval, pidx, done);
        k_merge<<<64, 512, 0, stream>>>(pmax, psum, pval, pidx, done,
                                        rowm, rows, rowv, rowi);
        k_upd2<<<1, 64, 0, stream>>>(i, rowm, rows, rowv, rowi,
                                     scores, last, fe, mlens, done, bwv);
        const int* sT = (i & 1) ? T0 : T1;
        int*       dT = (i & 1) ? T1 : T0;
        k_shuf_h<<<64, 256, 0, stream>>>(i, sT, dT, bwv, done, last,
                                         emb, ctx, lemb, tlang, hT);
    }
    // 74 steps (even count) -> final tokens land back in T0
    k_out<<<5, 256, 0, stream>>>(T0, scores, (float*)d_out);
}